// Round 1
// baseline (3993.948 us; speedup 1.0000x reference)
//
#include <hip/hip_runtime.h>
#include <math.h>

#define N_TOK 131072
#define DIM   64
#define QS    8
#define KS    1024

// Precompute per-codeword squared norms: dc2[q*K+k] = sum_d c[q,k,d]^2
__global__ void dc2_kernel(const float* __restrict__ cb, float* __restrict__ dc2) {
    int i = blockIdx.x * blockDim.x + threadIdx.x;   // q*K + k
    if (i < QS * KS) {
        const float* c = cb + (size_t)i * DIM;
        float s = 0.f;
#pragma unroll
        for (int d = 0; d < DIM; ++d) s = fmaf(c[d], c[d], s);
        dc2[i] = s;
    }
}

// One thread per token. Residual lives in 64 VGPRs across all 8 stages.
__global__ __launch_bounds__(256, 2)
void rvq_kernel(const float* __restrict__ x,
                const float* __restrict__ cb,
                const float* __restrict__ dc2,
                float* __restrict__ out) {
    const int n = blockIdx.x * blockDim.x + threadIdx.x;

    const float* xr = x + (size_t)n * DIM;
    float r[DIM];
#pragma unroll
    for (int d = 0; d < DIM; d += 4) {
        float4 v = *(const float4*)(xr + d);
        r[d] = v.x; r[d+1] = v.y; r[d+2] = v.z; r[d+3] = v.w;
    }

    float lossAcc[QS];
    int   idxOut[QS];

    for (int q = 0; q < QS; ++q) {
        const float* cq = cb  + (size_t)q * KS * DIM;   // wave-uniform base
        const float* dq = dc2 + q * KS;

        float dr2 = 0.f;
#pragma unroll
        for (int d = 0; d < DIM; ++d) dr2 = fmaf(r[d], r[d], dr2);

        float best = INFINITY;
        int   bidx = 0;

        for (int k = 0; k < KS; k += 4) {
            const float* c0 = cq + (size_t)k * DIM;     // uniform -> s_load path
            float a0 = 0.f, a1 = 0.f, a2 = 0.f, a3 = 0.f;
#pragma unroll
            for (int d = 0; d < DIM; ++d) {
                float rd = r[d];
                a0 = fmaf(rd, c0[d          ], a0);
                a1 = fmaf(rd, c0[d +   DIM  ], a1);
                a2 = fmaf(rd, c0[d + 2*DIM  ], a2);
                a3 = fmaf(rd, c0[d + 3*DIM  ], a3);
            }
            float d0 = fmaf(-2.f, a0, dr2) + dq[k    ];
            float d1 = fmaf(-2.f, a1, dr2) + dq[k + 1];
            float d2 = fmaf(-2.f, a2, dr2) + dq[k + 2];
            float d3 = fmaf(-2.f, a3, dr2) + dq[k + 3];
            // strict < keeps the first (lowest-index) minimum, matching argmin
            if (d0 < best) { best = d0; bidx = k;     }
            if (d1 < best) { best = d1; bidx = k + 1; }
            if (d2 < best) { best = d2; bidx = k + 2; }
            if (d3 < best) { best = d3; bidx = k + 3; }
        }

        // gather chosen codeword, update residual, per-stage loss = sum(r_new^2)
        const float* cbest = cq + (size_t)bidx * DIM;   // divergent gather (L2-hot)
        float ls = 0.f;
#pragma unroll
        for (int d = 0; d < DIM; d += 4) {
            float4 cv = *(const float4*)(cbest + d);
            r[d]   -= cv.x;  r[d+1] -= cv.y;  r[d+2] -= cv.z;  r[d+3] -= cv.w;
            ls = fmaf(r[d],   r[d],   ls);
            ls = fmaf(r[d+1], r[d+1], ls);
            ls = fmaf(r[d+2], r[d+2], ls);
            ls = fmaf(r[d+3], r[d+3], ls);
        }
        lossAcc[q] = ls;
        idxOut[q]  = bidx;
    }

    // xq = x - r_final
    float* xq = out + (size_t)n * DIM;
#pragma unroll
    for (int d = 0; d < DIM; d += 4) {
        float4 v = *(const float4*)(xr + d);
        float4 o;
        o.x = v.x - r[d];   o.y = v.y - r[d+1];
        o.z = v.z - r[d+2]; o.w = v.w - r[d+3];
        *(float4*)(xq + d) = o;
    }

    // indices (as float values; whole out buffer is read as fp32)
    float* idxp = out + (size_t)N_TOK * DIM + (size_t)n * QS;
#pragma unroll
    for (int q = 0; q < QS; ++q) idxp[q] = (float)idxOut[q];

    // losses: wave shuffle-reduce -> LDS across 4 waves -> one atomicAdd per block
    __shared__ float lred[4][QS];
    const int lane = threadIdx.x & 63;
    const int wave = threadIdx.x >> 6;
#pragma unroll
    for (int q = 0; q < QS; ++q) {
        float v = lossAcc[q];
#pragma unroll
        for (int off = 32; off > 0; off >>= 1) v += __shfl_down(v, off, 64);
        if (lane == 0) lred[wave][q] = v;
    }
    __syncthreads();
    if (threadIdx.x < QS) {
        float s = lred[0][threadIdx.x] + lred[1][threadIdx.x]
                + lred[2][threadIdx.x] + lred[3][threadIdx.x];
        atomicAdd(out + (size_t)N_TOK * DIM + (size_t)N_TOK * QS + threadIdx.x,
                  s * (1.0f / ((float)N_TOK * (float)DIM)));
    }
}

extern "C" void kernel_launch(void* const* d_in, const int* in_sizes, int n_in,
                              void* d_out, int out_size, void* d_ws, size_t ws_size,
                              hipStream_t stream) {
    const float* x   = (const float*)d_in[0];   // (N, D)
    const float* cb  = (const float*)d_in[1];   // (Q, K, D)
    float*       out = (float*)d_out;           // [xq | indices | losses]
    float*       dc2 = (float*)d_ws;            // Q*K floats = 32 KB scratch

    // zero the 8 loss accumulators (harness poisons d_out before every launch)
    hipMemsetAsync(out + (size_t)N_TOK * DIM + (size_t)N_TOK * QS, 0,
                   QS * sizeof(float), stream);

    dc2_kernel<<<(QS * KS + 255) / 256, 256, 0, stream>>>(cb, dc2);
    rvq_kernel<<<N_TOK / 256, 256, 0, stream>>>(x, cb, dc2, out);
}

// Round 2
// 1220.366 us; speedup vs baseline: 3.2727x; 3.2727x over previous
//
#include <hip/hip_runtime.h>
#include <math.h>

#define N_TOK 131072
#define DIM   64
#define QS    8
#define KS    1024
#define CHUNK 128              // codewords staged in LDS per iteration
#define LPAD  72               // LDS row stride in f16 elems (144B: 16B-aligned, uniform banks)

typedef _Float16 f16x8 __attribute__((ext_vector_type(8)));
typedef float    f32x4 __attribute__((ext_vector_type(4)));

// ---- pre-pass 1: split fp32 codebook into two f16 limbs (lo limb scaled by 2^11) ----
__global__ void conv_kernel(const float* __restrict__ cb,
                            _Float16* __restrict__ ch, _Float16* __restrict__ cl) {
    int i = blockIdx.x * blockDim.x + threadIdx.x;
    if (i < QS * KS * DIM) {
        float c = cb[i];
        _Float16 hi = (_Float16)c;
        ch[i] = hi;
        cl[i] = (_Float16)((c - (float)hi) * 2048.0f);   // scaled: stays in normal f16 range
    }
}

// ---- pre-pass 2: exact fp32 codeword squared norms ----
__global__ void dc2_kernel(const float* __restrict__ cb, float* __restrict__ dc2) {
    int i = blockIdx.x * blockDim.x + threadIdx.x;
    if (i < QS * KS) {
        const float* c = cb + (size_t)i * DIM;
        float s = 0.f;
#pragma unroll
        for (int d = 0; d < DIM; ++d) s = fmaf(c[d], c[d], s);
        dc2[i] = s;
    }
}

// ---- main: block = 4 waves = 128 tokens, residual persistent in A-frag layout ----
__global__ __launch_bounds__(256, 3)
void rvq_mfma_kernel(const float* __restrict__ x,
                     const float* __restrict__ cbf,
                     const _Float16* __restrict__ chg,
                     const _Float16* __restrict__ clg,
                     const float* __restrict__ dc2,
                     float* __restrict__ out) {
    __shared__ _Float16 lh[CHUNK][LPAD];    // 18 KB  hi limb chunk
    __shared__ _Float16 ll[CHUNK][LPAD];    // 18 KB  lo limb chunk
    __shared__ int idxLDS[4][32];           // per-wave argmin broadcast

    const int tid  = threadIdx.x;
    const int wave = tid >> 6;
    const int lane = tid & 63;
    const int quad = lane >> 4;             // A/B frag: k-group;  C/D frag: row-group
    const int m    = lane & 15;             // A frag: token row;  B frag: codeword; C/D: col

    const int tokenBase = blockIdx.x * 128 + wave * 32;   // 2 row-tiles of 16 tokens

    // residual in A-frag layout: r[tile][h*8+j] = R[token][ (h?32:0) + quad*8 + j ]
    float r[2][16];
#pragma unroll
    for (int t = 0; t < 2; ++t) {
        const float* xp = x + (size_t)(tokenBase + t * 16 + m) * DIM + quad * 8;
        float4 a0 = *(const float4*)(xp);
        float4 a1 = *(const float4*)(xp + 4);
        float4 a2 = *(const float4*)(xp + 32);
        float4 a3 = *(const float4*)(xp + 36);
        r[t][0]=a0.x; r[t][1]=a0.y; r[t][2]=a0.z;  r[t][3]=a0.w;
        r[t][4]=a1.x; r[t][5]=a1.y; r[t][6]=a1.z;  r[t][7]=a1.w;
        r[t][8]=a2.x; r[t][9]=a2.y; r[t][10]=a2.z; r[t][11]=a2.w;
        r[t][12]=a3.x;r[t][13]=a3.y;r[t][14]=a3.z; r[t][15]=a3.w;
    }

    for (int q = 0; q < QS; ++q) {
        const _Float16* chq = chg + (size_t)q * KS * DIM;
        const _Float16* clq = clg + (size_t)q * KS * DIM;
        const float*    dq  = dc2 + q * KS;
        const float*    cfq = cbf + (size_t)q * KS * DIM;

        // split residual into f16 limbs (A-frags)
        f16x8 ah[2][2], al[2][2];
#pragma unroll
        for (int t = 0; t < 2; ++t)
#pragma unroll
            for (int h = 0; h < 2; ++h)
#pragma unroll
                for (int j = 0; j < 8; ++j) {
                    float v = r[t][h * 8 + j];
                    _Float16 hi = (_Float16)v;
                    ah[t][h][j] = hi;
                    al[t][h][j] = (_Float16)((v - (float)hi) * 2048.0f);
                }

        float bestv[2][4];
        int   besti[2][4];
#pragma unroll
        for (int t = 0; t < 2; ++t)
#pragma unroll
            for (int i = 0; i < 4; ++i) { bestv[t][i] = INFINITY; besti[t][i] = 0; }

        for (int k0 = 0; k0 < KS; k0 += CHUNK) {
            __syncthreads();
            {   // cooperative stage of 128 codewords x 64 dims x 2 limbs
                const int row = tid >> 1;
                const int col = (tid & 1) * 32;
                const uint4* gh = (const uint4*)(chq + (size_t)(k0 + row) * DIM + col);
                const uint4* gl = (const uint4*)(clq + (size_t)(k0 + row) * DIM + col);
                uint4 h0 = gh[0], h1 = gh[1], h2 = gh[2], h3 = gh[3];
                uint4 l0 = gl[0], l1 = gl[1], l2 = gl[2], l3 = gl[3];
                *(uint4*)&lh[row][col]      = h0;  *(uint4*)&lh[row][col + 8]  = h1;
                *(uint4*)&lh[row][col + 16] = h2;  *(uint4*)&lh[row][col + 24] = h3;
                *(uint4*)&ll[row][col]      = l0;  *(uint4*)&ll[row][col + 8]  = l1;
                *(uint4*)&ll[row][col + 16] = l2;  *(uint4*)&ll[row][col + 24] = l3;
            }
            __syncthreads();

            for (int nn = 0; nn < CHUNK; nn += 16) {
                const _Float16* bh = &lh[nn + m][quad * 8];
                const _Float16* bl = &ll[nn + m][quad * 8];
                f16x8 bh0 = *(const f16x8*)bh;
                f16x8 bh1 = *(const f16x8*)(bh + 32);
                f16x8 bl0 = *(const f16x8*)bl;
                f16x8 bl1 = *(const f16x8*)(bl + 32);
                const float dval = dq[k0 + nn + m];       // ||c||^2 for this lane's col
                const int   cidx = k0 + nn + m;
#pragma unroll
                for (int t = 0; t < 2; ++t) {
                    f32x4 zero = {0.f, 0.f, 0.f, 0.f};
                    f32x4 hh = __builtin_amdgcn_mfma_f32_16x16x32_f16(ah[t][0], bh0, zero, 0, 0, 0);
                    hh = __builtin_amdgcn_mfma_f32_16x16x32_f16(ah[t][1], bh1, hh, 0, 0, 0);
                    f32x4 tx = __builtin_amdgcn_mfma_f32_16x16x32_f16(ah[t][0], bl0, zero, 0, 0, 0);
                    tx = __builtin_amdgcn_mfma_f32_16x16x32_f16(ah[t][1], bl1, tx, 0, 0, 0);
                    tx = __builtin_amdgcn_mfma_f32_16x16x32_f16(al[t][0], bh0, tx, 0, 0, 0);
                    tx = __builtin_amdgcn_mfma_f32_16x16x32_f16(al[t][1], bh1, tx, 0, 0, 0);
#pragma unroll
                    for (int i = 0; i < 4; ++i) {
                        // dist - ||r||^2 = ||c||^2 - 2*(hh + 2^-11 * cross)
                        float s = fmaf(-2.f, fmaf(4.8828125e-4f, tx[i], hh[i]), dval);
                        if (s < bestv[t][i]) { bestv[t][i] = s; besti[t][i] = cidx; }
                    }
                }
            }
        }

        // cross-lane argmin over the 16 cols (tie-break: lowest index, matching argmin)
#pragma unroll
        for (int mask = 1; mask <= 8; mask <<= 1) {
#pragma unroll
            for (int t = 0; t < 2; ++t)
#pragma unroll
                for (int i = 0; i < 4; ++i) {
                    float ov = __shfl_xor(bestv[t][i], mask, 64);
                    int   oi = __shfl_xor(besti[t][i], mask, 64);
                    if (ov < bestv[t][i] || (ov == bestv[t][i] && oi < besti[t][i])) {
                        bestv[t][i] = ov; besti[t][i] = oi;
                    }
                }
        }

        // writer lanes (m==0): emit indices + broadcast via LDS
        if (m == 0) {
#pragma unroll
            for (int t = 0; t < 2; ++t)
#pragma unroll
                for (int i = 0; i < 4; ++i) {
                    int row = quad * 4 + i;                     // C/D row = token-in-tile
                    int tok = tokenBase + t * 16 + row;
                    idxLDS[wave][t * 16 + row] = besti[t][i];
                    out[(size_t)N_TOK * DIM + (size_t)tok * QS + q] = (float)besti[t][i];
                }
        }
        __syncthreads();

        // residual update: exact fp32 gather of the chosen codeword (matches reference)
        float ls = 0.f;
#pragma unroll
        for (int t = 0; t < 2; ++t) {
            int id = idxLDS[wave][t * 16 + m];                  // this lane's A-frag token
            const float* cp = cfq + (size_t)id * DIM + quad * 8;
            float4 c0 = *(const float4*)(cp);
            float4 c1 = *(const float4*)(cp + 4);
            float4 c2 = *(const float4*)(cp + 32);
            float4 c3 = *(const float4*)(cp + 36);
            r[t][0]-=c0.x;  r[t][1]-=c0.y;  r[t][2]-=c0.z;  r[t][3]-=c0.w;
            r[t][4]-=c1.x;  r[t][5]-=c1.y;  r[t][6]-=c1.z;  r[t][7]-=c1.w;
            r[t][8]-=c2.x;  r[t][9]-=c2.y;  r[t][10]-=c2.z; r[t][11]-=c2.w;
            r[t][12]-=c3.x; r[t][13]-=c3.y; r[t][14]-=c3.z; r[t][15]-=c3.w;
#pragma unroll
            for (int j = 0; j < 16; ++j) ls = fmaf(r[t][j], r[t][j], ls);
        }
        // per-stage commitment loss: wave-reduce then one atomic per wave
#pragma unroll
        for (int mask = 1; mask <= 32; mask <<= 1) ls += __shfl_xor(ls, mask, 64);
        if (lane == 0)
            atomicAdd(out + (size_t)N_TOK * DIM + (size_t)N_TOK * QS + q,
                      ls * (1.0f / ((float)N_TOK * (float)DIM)));
    }

    // xq = x - r_final
#pragma unroll
    for (int t = 0; t < 2; ++t) {
        const size_t rowoff = (size_t)(tokenBase + t * 16 + m) * DIM + quad * 8;
        const float* xp = x + rowoff;
        float*       op = out + rowoff;
        float4 a0 = *(const float4*)(xp);
        float4 a1 = *(const float4*)(xp + 4);
        float4 a2 = *(const float4*)(xp + 32);
        float4 a3 = *(const float4*)(xp + 36);
        float4 o0, o1, o2, o3;
        o0.x=a0.x-r[t][0];  o0.y=a0.y-r[t][1];  o0.z=a0.z-r[t][2];  o0.w=a0.w-r[t][3];
        o1.x=a1.x-r[t][4];  o1.y=a1.y-r[t][5];  o1.z=a1.z-r[t][6];  o1.w=a1.w-r[t][7];
        o2.x=a2.x-r[t][8];  o2.y=a2.y-r[t][9];  o2.z=a2.z-r[t][10]; o2.w=a2.w-r[t][11];
        o3.x=a3.x-r[t][12]; o3.y=a3.y-r[t][13]; o3.z=a3.z-r[t][14]; o3.w=a3.w-r[t][15];
        *(float4*)(op)      = o0;
        *(float4*)(op + 4)  = o1;
        *(float4*)(op + 32) = o2;
        *(float4*)(op + 36) = o3;
    }
}

extern "C" void kernel_launch(void* const* d_in, const int* in_sizes, int n_in,
                              void* d_out, int out_size, void* d_ws, size_t ws_size,
                              hipStream_t stream) {
    const float* x   = (const float*)d_in[0];   // (N, D)
    const float* cb  = (const float*)d_in[1];   // (Q, K, D)
    float*       out = (float*)d_out;           // [xq | indices | losses]
    char*        ws  = (char*)d_ws;

    _Float16* ch  = (_Float16*)ws;                        // 1 MB
    _Float16* cl  = (_Float16*)(ws + 1048576);            // 1 MB
    float*    dc2 = (float*)(ws + 2097152);               // 32 KB

    // zero the 8 loss accumulators (harness poisons d_out)
    hipMemsetAsync(out + (size_t)N_TOK * DIM + (size_t)N_TOK * QS, 0,
                   QS * sizeof(float), stream);

    conv_kernel<<<(QS * KS * DIM + 255) / 256, 256, 0, stream>>>(cb, ch, cl);
    dc2_kernel<<<(QS * KS + 255) / 256, 256, 0, stream>>>(cb, dc2);
    rvq_mfma_kernel<<<N_TOK / 128, 256, 0, stream>>>(x, cb, ch, cl, dc2, out);
}

// Round 3
// 1042.155 us; speedup vs baseline: 3.8324x; 1.1710x over previous
//
#include <hip/hip_runtime.h>
#include <math.h>

#define N_TOK 131072
#define DIM   64
#define QS    8
#define KS    1024
#define CHUNK 128              // codewords staged in LDS per iteration

typedef _Float16 f16x8 __attribute__((ext_vector_type(8)));
typedef float    f32x4 __attribute__((ext_vector_type(4)));

#define AS1C(p) ((const __attribute__((address_space(1))) void*)(p))
#define AS3(p)  ((__attribute__((address_space(3))) void*)(p))

// ---- pre-pass 1: split fp32 codebook into two f16 limbs (lo limb scaled by 2^11) ----
__global__ void conv_kernel(const float* __restrict__ cb,
                            _Float16* __restrict__ ch, _Float16* __restrict__ cl) {
    int i = blockIdx.x * blockDim.x + threadIdx.x;
    if (i < QS * KS * DIM) {
        float c = cb[i];
        _Float16 hi = (_Float16)c;
        ch[i] = hi;
        cl[i] = (_Float16)((c - (float)hi) * 2048.0f);   // scaled: stays in normal f16 range
    }
}

// ---- pre-pass 2: exact fp32 codeword squared norms ----
__global__ void dc2_kernel(const float* __restrict__ cb, float* __restrict__ dc2) {
    int i = blockIdx.x * blockDim.x + threadIdx.x;
    if (i < QS * KS) {
        const float* c = cb + (size_t)i * DIM;
        float s = 0.f;
#pragma unroll
        for (int d = 0; d < DIM; ++d) s = fmaf(c[d], c[d], s);
        dc2[i] = s;
    }
}

// ---- main: 4 waves/block, ONE 16-token tile per wave (low VGPR pressure) ----
// LDS codebook chunk in fragment-major layout [nn][half][limb][lane][8]:
//   - global_load_lds forced layout (uniform base + lane*16B)  [m104]
//   - b128 reads at lane*16 are conflict-free
__global__ __launch_bounds__(256, 4)
void rvq_mfma_kernel(const float* __restrict__ x,
                     const float* __restrict__ cbf,
                     const _Float16* __restrict__ chg,
                     const _Float16* __restrict__ clg,
                     const float* __restrict__ dc2,
                     float* __restrict__ out) {
    __shared__ _Float16 lbuf[CHUNK / 16][2][2][64][8];   // 32 KB
    __shared__ int idxLDS[4][16];

    const int tid  = threadIdx.x;
    const int wave = tid >> 6;
    const int lane = tid & 63;
    const int quad = lane >> 4;      // A frag: k-group; C/D: row-group
    const int m    = lane & 15;      // A frag: token row; B frag/C-D col: codeword

    const int tokenBase = blockIdx.x * 64 + wave * 16;
    const int myTok     = tokenBase + m;

    // residual in A-frag layout: r[j]    = R[tok=m][quad*8 + j]        (j<8)
    //                            r[8+j]  = R[tok=m][32 + quad*8 + j]
    float r[16];
    {
        const float* xp = x + (size_t)myTok * DIM + quad * 8;
        f32x4 a0 = __builtin_nontemporal_load((const f32x4*)(xp));
        f32x4 a1 = __builtin_nontemporal_load((const f32x4*)(xp + 4));
        f32x4 a2 = __builtin_nontemporal_load((const f32x4*)(xp + 32));
        f32x4 a3 = __builtin_nontemporal_load((const f32x4*)(xp + 36));
#pragma unroll
        for (int i = 0; i < 4; ++i) {
            r[i] = a0[i]; r[4+i] = a1[i]; r[8+i] = a2[i]; r[12+i] = a3[i];
        }
    }

    int idxAcc[QS];     // this lane's token's chosen index per stage

    for (int q = 0; q < QS; ++q) {
        const _Float16* chq = chg + (size_t)q * KS * DIM;
        const _Float16* clq = clg + (size_t)q * KS * DIM;
        const float*    dq  = dc2 + q * KS;
        const float*    cfq = cbf + (size_t)q * KS * DIM;

        // split residual into f16 limbs (A-frags)
        f16x8 ah0, ah1, al0, al1;
#pragma unroll
        for (int j = 0; j < 8; ++j) {
            float v0 = r[j], v1 = r[8 + j];
            _Float16 h0 = (_Float16)v0, h1 = (_Float16)v1;
            ah0[j] = h0;                             ah1[j] = h1;
            al0[j] = (_Float16)((v0 - (float)h0) * 2048.0f);
            al1[j] = (_Float16)((v1 - (float)h1) * 2048.0f);
        }

        float bestv[4];
        int   besti[4];
#pragma unroll
        for (int i = 0; i < 4; ++i) { bestv[i] = INFINITY; besti[i] = 0; }

        for (int k0 = 0; k0 < KS; k0 += CHUNK) {
            __syncthreads();                      // prior chunk's reads done
            // async stage: each wave loads 2 nn-tiles x 2 halves x 2 limbs (8x 1KB)
#pragma unroll
            for (int t2 = 0; t2 < 2; ++t2) {
                const int nn  = wave * 2 + t2;
                const int row = k0 + nn * 16 + m;
                const size_t goff = (size_t)row * DIM + quad * 8;   // lane's 16B
#pragma unroll
                for (int half = 0; half < 2; ++half) {
                    __builtin_amdgcn_global_load_lds(AS1C(chq + goff + half * 32),
                        AS3(&lbuf[nn][half][0][0][0]), 16, 0, 0);
                    __builtin_amdgcn_global_load_lds(AS1C(clq + goff + half * 32),
                        AS3(&lbuf[nn][half][1][0][0]), 16, 0, 0);
                }
            }
            __syncthreads();                      // barrier drains vmcnt [m97]

#pragma unroll
            for (int nn = 0; nn < CHUNK / 16; ++nn) {
                f16x8 bh0 = *(const f16x8*)&lbuf[nn][0][0][lane][0];
                f16x8 bh1 = *(const f16x8*)&lbuf[nn][1][0][lane][0];
                f16x8 bl0 = *(const f16x8*)&lbuf[nn][0][1][lane][0];
                f16x8 bl1 = *(const f16x8*)&lbuf[nn][1][1][lane][0];
                const float dval = dq[k0 + nn * 16 + m];   // ||c||^2, this lane's col
                const int   cidx = k0 + nn * 16 + m;

                f32x4 zero = {0.f, 0.f, 0.f, 0.f};
                f32x4 hh = __builtin_amdgcn_mfma_f32_16x16x32_f16(ah0, bh0, zero, 0, 0, 0);
                hh = __builtin_amdgcn_mfma_f32_16x16x32_f16(ah1, bh1, hh, 0, 0, 0);
                f32x4 tx = __builtin_amdgcn_mfma_f32_16x16x32_f16(ah0, bl0, zero, 0, 0, 0);
                tx = __builtin_amdgcn_mfma_f32_16x16x32_f16(ah1, bl1, tx, 0, 0, 0);
                tx = __builtin_amdgcn_mfma_f32_16x16x32_f16(al0, bh0, tx, 0, 0, 0);
                tx = __builtin_amdgcn_mfma_f32_16x16x32_f16(al1, bh1, tx, 0, 0, 0);
#pragma unroll
                for (int i = 0; i < 4; ++i) {
                    // dist - ||r||^2 = ||c||^2 - 2*(hh + 2^-11 * cross)
                    float s = fmaf(-2.f, fmaf(4.8828125e-4f, tx[i], hh[i]), dval);
                    if (s < bestv[i]) { bestv[i] = s; besti[i] = cidx; }
                }
            }
        }

        // cross-lane argmin over the 16 cols (tie-break: lowest index, matches argmin)
#pragma unroll
        for (int mask = 1; mask <= 8; mask <<= 1) {
#pragma unroll
            for (int i = 0; i < 4; ++i) {
                float ov = __shfl_xor(bestv[i], mask, 64);
                int   oi = __shfl_xor(besti[i], mask, 64);
                if (ov < bestv[i] || (ov == bestv[i] && oi < besti[i])) {
                    bestv[i] = ov; besti[i] = oi;
                }
            }
        }

        // broadcast per-row winners to the lanes that own those tokens
        if (m == 0) {
#pragma unroll
            for (int i = 0; i < 4; ++i) idxLDS[wave][quad * 4 + i] = besti[i];
        }
        __syncthreads();
        const int id = idxLDS[wave][m];
        idxAcc[q] = id;

        // residual update: exact fp32 gather of chosen codeword (matches reference)
        float ls = 0.f;
        {
            const float* cp = cfq + (size_t)id * DIM + quad * 8;
            f32x4 c0 = *(const f32x4*)(cp);
            f32x4 c1 = *(const f32x4*)(cp + 4);
            f32x4 c2 = *(const f32x4*)(cp + 32);
            f32x4 c3 = *(const f32x4*)(cp + 36);
#pragma unroll
            for (int i = 0; i < 4; ++i) {
                r[i]    -= c0[i];  r[4+i]  -= c1[i];
                r[8+i]  -= c2[i];  r[12+i] -= c3[i];
            }
#pragma unroll
            for (int j = 0; j < 16; ++j) ls = fmaf(r[j], r[j], ls);
        }
        // per-stage commitment loss: wave-reduce then one atomic per wave
#pragma unroll
        for (int mask = 1; mask <= 32; mask <<= 1) ls += __shfl_xor(ls, mask, 64);
        if (lane == 0)
            atomicAdd(out + (size_t)N_TOK * DIM + (size_t)N_TOK * QS + q,
                      ls * (1.0f / ((float)N_TOK * (float)DIM)));
    }

    // xq = x - r_final   (streaming: non-temporal)
    {
        const size_t rowoff = (size_t)myTok * DIM + quad * 8;
        const float* xp = x + rowoff;
        float*       op = out + rowoff;
        f32x4 a0 = __builtin_nontemporal_load((const f32x4*)(xp));
        f32x4 a1 = __builtin_nontemporal_load((const f32x4*)(xp + 4));
        f32x4 a2 = __builtin_nontemporal_load((const f32x4*)(xp + 32));
        f32x4 a3 = __builtin_nontemporal_load((const f32x4*)(xp + 36));
        f32x4 o0, o1, o2, o3;
#pragma unroll
        for (int i = 0; i < 4; ++i) {
            o0[i] = a0[i] - r[i];     o1[i] = a1[i] - r[4+i];
            o2[i] = a2[i] - r[8+i];   o3[i] = a3[i] - r[12+i];
        }
        __builtin_nontemporal_store(o0, (f32x4*)(op));
        __builtin_nontemporal_store(o1, (f32x4*)(op + 4));
        __builtin_nontemporal_store(o2, (f32x4*)(op + 32));
        __builtin_nontemporal_store(o3, (f32x4*)(op + 36));
    }

    // indices: one coalesced 32B store per token (quad 0 lanes only)
    if (quad == 0) {
        float* idxp = out + (size_t)N_TOK * DIM + (size_t)myTok * QS;
        f32x4 i0, i1;
#pragma unroll
        for (int i = 0; i < 4; ++i) { i0[i] = (float)idxAcc[i]; i1[i] = (float)idxAcc[4+i]; }
        __builtin_nontemporal_store(i0, (f32x4*)(idxp));
        __builtin_nontemporal_store(i1, (f32x4*)(idxp + 4));
    }
}

extern "C" void kernel_launch(void* const* d_in, const int* in_sizes, int n_in,
                              void* d_out, int out_size, void* d_ws, size_t ws_size,
                              hipStream_t stream) {
    const float* x   = (const float*)d_in[0];   // (N, D)
    const float* cb  = (const float*)d_in[1];   // (Q, K, D)
    float*       out = (float*)d_out;           // [xq | indices | losses]
    char*        ws  = (char*)d_ws;

    _Float16* ch  = (_Float16*)ws;                        // 1 MB
    _Float16* cl  = (_Float16*)(ws + 1048576);            // 1 MB
    float*    dc2 = (float*)(ws + 2097152);               // 32 KB

    // zero the 8 loss accumulators (harness poisons d_out)
    hipMemsetAsync(out + (size_t)N_TOK * DIM + (size_t)N_TOK * QS, 0,
                   QS * sizeof(float), stream);

    conv_kernel<<<(QS * KS * DIM + 255) / 256, 256, 0, stream>>>(cb, ch, cl);
    dc2_kernel<<<(QS * KS + 255) / 256, 256, 0, stream>>>(cb, dc2);
    rvq_mfma_kernel<<<N_TOK / 64, 256, 0, stream>>>(x, cb, ch, cl, dc2, out);
}